// Round 4
// baseline (13997.841 us; speedup 1.0000x reference)
//
#include <hip/hip_runtime.h>
#include <hip/hip_bf16.h>

#define TB 4096   // T*B
#define NB 32     // B
#define NT 128    // T
#define H 256

// ---------------------------------------------------------------------------
// K1: conv1(8x8 s4)+relu -> S1(LDS) -> conv2(4x4 s2)+relu, one image/block.
// (unchanged)
// ---------------------------------------------------------------------------
__global__ __launch_bounds__(256) void conv_front2(
    const float* __restrict__ x,
    const float* __restrict__ w1, const float* __restrict__ b1,
    const float* __restrict__ w2, const float* __restrict__ b2,
    float* __restrict__ y2)
{
    __shared__ float S1[16 * 400];        // conv1 out [16][400], 25.6 KB

    const int img = blockIdx.x;
    const int tid = threadIdx.x;
    const int ws  = __builtin_amdgcn_readfirstlane(tid >> 6);  // wave id (uniform)
    const int l   = tid & 63;

    const float* xi = x + (size_t)img * 4 * 84 * 84;

    // ---------------- conv1 ----------------
    int iyv[6], ixv[6];
    #pragma unroll
    for (int p = 0; p < 6; p++) {
        const int pos = l + (p << 6);
        iyv[p] = (pos / 20) * 4;
        ixv[p] = (pos % 20) * 4;
    }
    const int pos6 = l + 384;
    const int iy6 = (pos6 / 20) * 4, ix6 = (pos6 % 20) * 4;
    const bool t6 = (l < 16);

    float acc[4][7];
    #pragma unroll
    for (int c = 0; c < 4; c++) {
        const float bv = b1[4 * ws + c];
        #pragma unroll
        for (int p = 0; p < 7; p++) acc[c][p] = bv;
    }

    for (int ci = 0; ci < 4; ci++) {
        #pragma unroll 1
        for (int ky = 0; ky < 8; ky++) {
            float4 wa[4], wb[4];
            #pragma unroll
            for (int c = 0; c < 4; c++) {
                const float* wr = w1 + (((4 * ws + c) * 4 + ci) * 8 + ky) * 8;
                wa[c] = *(const float4*)wr;
                wb[c] = *(const float4*)(wr + 4);
            }
            const float* xrow = xi + ci * 7056 + ky * 84;
            #pragma unroll
            for (int p = 0; p < 6; p++) {
                const float* xr = xrow + iyv[p] * 84 + ixv[p];
                const float4 x0 = *(const float4*)xr;
                const float4 x1 = *(const float4*)(xr + 4);
                #pragma unroll
                for (int c = 0; c < 4; c++)
                    acc[c][p] += x0.x * wa[c].x + x0.y * wa[c].y + x0.z * wa[c].z + x0.w * wa[c].w
                               + x1.x * wb[c].x + x1.y * wb[c].y + x1.z * wb[c].z + x1.w * wb[c].w;
            }
            if (t6) {
                const float* xr = xrow + iy6 * 84 + ix6;
                const float4 x0 = *(const float4*)xr;
                const float4 x1 = *(const float4*)(xr + 4);
                #pragma unroll
                for (int c = 0; c < 4; c++)
                    acc[c][6] += x0.x * wa[c].x + x0.y * wa[c].y + x0.z * wa[c].z + x0.w * wa[c].w
                               + x1.x * wb[c].x + x1.y * wb[c].y + x1.z * wb[c].z + x1.w * wb[c].w;
            }
        }
    }
    #pragma unroll
    for (int c = 0; c < 4; c++) {
        #pragma unroll
        for (int p = 0; p < 6; p++)
            S1[(4 * ws + c) * 400 + l + (p << 6)] = fmaxf(acc[c][p], 0.f);
        if (t6)
            S1[(4 * ws + c) * 400 + pos6] = fmaxf(acc[c][6], 0.f);
    }
    __syncthreads();

    // ---------------- conv2 ----------------
    const int oy0 = l / 9, ox0 = l % 9;
    const int p1 = l + 64;
    const bool t1 = (p1 < 81);
    const int oy1 = p1 / 9, ox1 = p1 % 9;

    float a2[8][2];
    #pragma unroll
    for (int c = 0; c < 8; c++) {
        const float bv = b2[8 * ws + c];
        a2[c][0] = bv; a2[c][1] = bv;
    }

    for (int ci = 0; ci < 16; ci++) {
        #pragma unroll 1
        for (int ky = 0; ky < 4; ky++) {
            float4 wv[8];
            #pragma unroll
            for (int c = 0; c < 8; c++)
                wv[c] = *(const float4*)(w2 + ((((8 * ws + c) * 16 + ci) * 16) + ky * 4));
            {
                const float* sr = &S1[ci * 400 + (oy0 * 2 + ky) * 20 + ox0 * 2];
                const float2 f0 = *(const float2*)sr;
                const float2 f1 = *(const float2*)(sr + 2);
                #pragma unroll
                for (int c = 0; c < 8; c++)
                    a2[c][0] += f0.x * wv[c].x + f0.y * wv[c].y + f1.x * wv[c].z + f1.y * wv[c].w;
            }
            if (t1) {
                const float* sr = &S1[ci * 400 + (oy1 * 2 + ky) * 20 + ox1 * 2];
                const float2 f0 = *(const float2*)sr;
                const float2 f1 = *(const float2*)(sr + 2);
                #pragma unroll
                for (int c = 0; c < 8; c++)
                    a2[c][1] += f0.x * wv[c].x + f0.y * wv[c].y + f1.x * wv[c].z + f1.y * wv[c].w;
            }
        }
    }
    float* yo = y2 + (size_t)img * 2592;
    #pragma unroll
    for (int c = 0; c < 8; c++) {
        yo[(8 * ws + c) * 81 + l] = fmaxf(a2[c][0], 0.f);
        if (t1) yo[(8 * ws + c) * 81 + p1] = fmaxf(a2[c][1], 0.f);
    }
}

// ---------------------------------------------------------------------------
// K2: register-tiled GEMM.  C[M,N] = act(A[M,K] @ W[N,K]^T + bias).
// (unchanged)
// ---------------------------------------------------------------------------
__global__ __launch_bounds__(256) void gemm64(
    const float* __restrict__ A, const float* __restrict__ W,
    const float* __restrict__ bias, float* __restrict__ C,
    int M, int N, int K, int relu, int AT, int CT)
{
    __shared__ float As[32][68];   // [k][m]
    __shared__ float Bs[32][68];   // [k][n]
    const int tid = threadIdx.x;
    const int m0 = blockIdx.x * 64;
    const int n0 = blockIdx.y * 64;
    const int tx = tid & 15, ty = tid >> 4;

    float acc[4][4];
    #pragma unroll
    for (int i = 0; i < 4; i++)
        #pragma unroll
        for (int j = 0; j < 4; j++) acc[i][j] = 0.f;

    for (int k0 = 0; k0 < K; k0 += 32) {
        if (AT) {
            #pragma unroll
            for (int r = 0; r < 2; r++) {
                const int f = tid + r * 256;
                const int kk = f >> 4, m4 = (f & 15) << 2;
                float4 v = make_float4(0.f, 0.f, 0.f, 0.f);
                if (k0 + kk < K) v = *(const float4*)&A[(size_t)(k0 + kk) * M + m0 + m4];
                *(float4*)&As[kk][m4] = v;
            }
        } else {
            #pragma unroll
            for (int r = 0; r < 2; r++) {
                const int f = tid + r * 256;
                const int mi = f >> 3, c4 = (f & 7) << 2;
                const int k = k0 + c4;
                const float* ar = &A[(size_t)(m0 + mi) * K];
                float4 v = make_float4(0.f, 0.f, 0.f, 0.f);
                if (k + 3 < K) v = *(const float4*)&ar[k];
                else {
                    if (k     < K) v.x = ar[k];
                    if (k + 1 < K) v.y = ar[k + 1];
                    if (k + 2 < K) v.z = ar[k + 2];
                }
                As[c4    ][mi] = v.x;
                As[c4 + 1][mi] = v.y;
                As[c4 + 2][mi] = v.z;
                As[c4 + 3][mi] = v.w;
            }
        }
        #pragma unroll
        for (int r = 0; r < 2; r++) {
            const int f = tid + r * 256;
            const int ni = f >> 3, kq = (f & 7) << 2;
            const int n = n0 + ni, k = k0 + kq;
            float4 v = make_float4(0.f, 0.f, 0.f, 0.f);
            if (n < N) {
                const float* wrow = &W[(size_t)n * K];
                if (k + 3 < K) v = *(const float4*)&wrow[k];
                else {
                    if (k     < K) v.x = wrow[k];
                    if (k + 1 < K) v.y = wrow[k + 1];
                    if (k + 2 < K) v.z = wrow[k + 2];
                }
            }
            Bs[kq    ][ni] = v.x;
            Bs[kq + 1][ni] = v.y;
            Bs[kq + 2][ni] = v.z;
            Bs[kq + 3][ni] = v.w;
        }
        __syncthreads();

        #pragma unroll
        for (int kk = 0; kk < 32; kk++) {
            const float4 a4 = *(const float4*)&As[kk][ty << 2];
            const float4 b4 = *(const float4*)&Bs[kk][tx << 2];
            const float av[4] = {a4.x, a4.y, a4.z, a4.w};
            const float bv[4] = {b4.x, b4.y, b4.z, b4.w};
            #pragma unroll
            for (int i = 0; i < 4; i++)
                #pragma unroll
                for (int j = 0; j < 4; j++)
                    acc[i][j] += av[i] * bv[j];
        }
        __syncthreads();
    }

    const int nb = n0 + (tx << 2);
    float bv4[4];
    #pragma unroll
    for (int j = 0; j < 4; j++)
        bv4[j] = (nb + j < N) ? bias[nb + j] : 0.f;

    if (!CT) {
        #pragma unroll
        for (int i = 0; i < 4; i++) {
            const int m = m0 + (ty << 2) + i;
            float4 v;
            v.x = acc[i][0] + bv4[0]; v.y = acc[i][1] + bv4[1];
            v.z = acc[i][2] + bv4[2]; v.w = acc[i][3] + bv4[3];
            if (relu) {
                v.x = fmaxf(v.x, 0.f); v.y = fmaxf(v.y, 0.f);
                v.z = fmaxf(v.z, 0.f); v.w = fmaxf(v.w, 0.f);
            }
            if (nb + 3 < N) *(float4*)&C[(size_t)m * N + nb] = v;
            else {
                if (nb     < N) C[(size_t)m * N + nb]     = v.x;
                if (nb + 1 < N) C[(size_t)m * N + nb + 1] = v.y;
                if (nb + 2 < N) C[(size_t)m * N + nb + 2] = v.z;
            }
        }
    } else {
        #pragma unroll
        for (int j = 0; j < 4; j++) {
            if (nb + j < N) {
                float4 v;
                v.x = acc[0][j] + bv4[j]; v.y = acc[1][j] + bv4[j];
                v.z = acc[2][j] + bv4[j]; v.w = acc[3][j] + bv4[j];
                if (relu) {
                    v.x = fmaxf(v.x, 0.f); v.y = fmaxf(v.y, 0.f);
                    v.z = fmaxf(v.z, 0.f); v.w = fmaxf(v.w, 0.f);
                }
                *(float4*)&C[(size_t)(nb + j) * M + m0 + (ty << 2)] = v;
            }
        }
    }
}

// ---------------------------------------------------------------------------
// scan_init: hg pingpong slot0 = gru_state verbatim ([2][32][256] == [g][256]
// with g = net*32+b), and zero the per-group sync counters.
// ---------------------------------------------------------------------------
__global__ __launch_bounds__(256) void scan_init(
    const float* __restrict__ g0, float* __restrict__ hg, int* __restrict__ cnt)
{
    const int i = blockIdx.x * 256 + threadIdx.x;   // 0..16383
    hg[i] = g0[i];
    if (i < 64) cnt[i] = 0;
}

// ---------------------------------------------------------------------------
// K3: GRU scan, weights REGISTER-RESIDENT.  Grid = 256 blocks (cooperative,
// 1/CU): group g = net*32+b (4 blocks), block r owns h-dims [64r, 64r+64)
// i.e. gate-rows {i, 256+i, 512+i}.  768 threads = 192 rows x 4 k-slices;
// each thread holds 16 float4 of whh in VGPRs, loaded ONCE (this removes the
// 786 KB/step/CU L2 weight stream that bounded gru_scan2 at 5.8 us/step).
// Per step: h (ping-pong global hg[2][64][256]) is staged into 4 bank-offset
// LDS replicas (conflict-free b128 reads), dot + 2x shfl_xor reduce, 64
// combiner threads emit the h slice; 4-block exchange via per-group release/
// acquire atomic counter (same fence+counter pattern as cg::grid_sync, but
// 4 blocks, same-XCD mapping r=bid>>6,g=bid&63).  Safety: hg[t&1] is only
// overwritten after cnt>=4(t+1), which requires all partners to have consumed
// it; cooperative launch guarantees co-residency so the spin cannot deadlock.
// ---------------------------------------------------------------------------
__global__ __launch_bounds__(768, 3) void gru_scan3(
    const float* __restrict__ gi,     // [2][4096][768] (bih added)
    const float* __restrict__ whh_a, const float* __restrict__ whh_c,
    const float* __restrict__ bhh_a, const float* __restrict__ bhh_c,
    const float* __restrict__ done,   // [4096]
    float* __restrict__ hg,           // [2 pp][64][256]
    int*   __restrict__ cnt,          // [64]
    float* __restrict__ hid,          // [2][4096][256] relu(h)
    float* __restrict__ hT)           // [2][32][256]
{
    const int bid = blockIdx.x;
    const int r4  = bid >> 6;         // slice 0..3 (same-XCD grouping)
    const int g   = bid & 63;
    const int net = g >> 5, b = g & 31;
    const int i0  = r4 << 6;
    const int tid = threadIdx.x;
    const int rl  = tid >> 2;         // row_local 0..191
    const int q   = tid & 3;          // k-slice 0..3
    const int g3  = rl >> 6;          // gate 0=r 1=z 2=n
    const int ii  = rl & 63;          // dim within slice

    const float* whh = net ? whh_c : whh_a;
    const float* bhh = net ? bhh_c : bhh_a;
    const float* gib = gi + (size_t)net * TB * 768;
    int* cg = cnt + g;

    __shared__ float hrep[4][264];    // 4 bank-offset replicas of masked h
    __shared__ float sb[192];         // row pre-activations

    // ---- weights -> VGPRs (once) ----
    float4 wv[16];
    {
        const float* wrow = whh + ((size_t)(g3 * 256 + i0 + ii) * 256) + q * 64;
        #pragma unroll
        for (int u = 0; u < 16; u++) wv[u] = *(const float4*)(wrow + 4 * u);
    }
    // combiner constants
    float bh_r = 0.f, bh_z = 0.f, bh_n = 0.f;
    if (tid < 64) {
        bh_r = bhh[i0 + tid];
        bh_z = bhh[256 + i0 + tid];
        bh_n = bhh[512 + i0 + tid];
    }

    for (int t = 0; t < NT; t++) {
        // ---- wait for h(t) (all 4 partner slices of step t-1 published) ----
        if (tid == 0) {
            const int target = 4 * t;
            while (__hip_atomic_load(cg, __ATOMIC_ACQUIRE,
                                     __HIP_MEMORY_SCOPE_AGENT) < target)
                __builtin_amdgcn_s_sleep(1);
        }
        __syncthreads();
        __threadfence();   // acquire: invalidate stale h lines

        const float d1 = 1.f - done[t * 32 + b];
        if (tid < 256) {
            const float hv = d1 * hg[((t & 1) * 64 + g) * 256 + tid];
            hrep[0][tid] = hv; hrep[1][tid] = hv;
            hrep[2][tid] = hv; hrep[3][tid] = hv;
        }
        __syncthreads();

        // ---- dot: 64 k per thread, weights in regs, h broadcast from LDS ----
        float acc = 0.f;
        const float* hq = &hrep[q][q * 64];
        #pragma unroll
        for (int u = 0; u < 16; u++) {
            const float4 h4 = *(const float4*)(hq + 4 * u);
            acc += wv[u].x * h4.x + wv[u].y * h4.y
                 + wv[u].z * h4.z + wv[u].w * h4.w;
        }
        acc += __shfl_xor(acc, 1);
        acc += __shfl_xor(acc, 2);
        if (q == 0) sb[rl] = acc;
        __syncthreads();

        // ---- combine gates, emit h slice ----
        if (tid < 64) {
            const int row = t * 32 + b;
            const float* gp = gib + (size_t)row * 768;
            const float s_r = sb[tid]        + bh_r + gp[i0 + tid];
            const float s_z = sb[64 + tid]   + bh_z + gp[256 + i0 + tid];
            const float s_n = sb[128 + tid]  + bh_n;
            const float gin = gp[512 + i0 + tid];
            const float rr = 1.f / (1.f + expf(-s_r));
            const float zz = 1.f / (1.f + expf(-s_z));
            const float nn = tanhf(gin + rr * s_n);
            const float hm = hrep[0][i0 + tid];          // masked h
            const float hnew = (1.f - zz) * nn + zz * hm;
            hg[(((t + 1) & 1) * 64 + g) * 256 + i0 + tid] = hnew;
            hid[((size_t)net * TB + row) * 256 + i0 + tid] = fmaxf(hnew, 0.f);
            if (t == NT - 1) hT[net * 8192 + b * 256 + i0 + tid] = hnew;
        }
        __threadfence();   // release: publish h slice before flag
        __syncthreads();
        if (tid == 0)
            __hip_atomic_fetch_add(cg, 1, __ATOMIC_RELEASE,
                                   __HIP_MEMORY_SCOPE_AGENT);
    }
}

// ---------------------------------------------------------------------------
// K5: heads — m2 arrives TRANSPOSED ([100][4096] per net).  (unchanged)
// ---------------------------------------------------------------------------
__global__ __launch_bounds__(256) void heads(
    const float* __restrict__ m2Ta, const float* __restrict__ m2Tc,
    const float* __restrict__ aw3, const float* __restrict__ ab3,
    const float* __restrict__ cw3, const float* __restrict__ cb3,
    const int* __restrict__ action,
    float* __restrict__ out)
{
    __shared__ float AW[700], AB[7], CW[100], CB1[1];
    const int tid = threadIdx.x;
    for (int f = tid; f < 700; f += 256) AW[f] = aw3[f];
    if (tid < 7)   AB[tid] = ab3[tid];
    if (tid < 100) CW[tid] = cw3[tid];
    if (tid == 0)  CB1[0] = cb3[0];
    __syncthreads();

    const int r = blockIdx.x * 256 + tid;

    float l[7];
    #pragma unroll
    for (int jj = 0; jj < 7; jj++) l[jj] = AB[jj];
    for (int k = 0; k < 100; k++) {
        const float mv = m2Ta[(size_t)k * TB + r];
        #pragma unroll
        for (int jj = 0; jj < 7; jj++) l[jj] += mv * AW[jj * 100 + k];
    }
    float mx = l[0];
    #pragma unroll
    for (int jj = 1; jj < 7; jj++) mx = fmaxf(mx, l[jj]);
    float se = 0.f;
    #pragma unroll
    for (int jj = 0; jj < 7; jj++) se += expf(l[jj] - mx);
    const float lse = logf(se);
    const int a = action[r];
    float ent = 0.f, lp_a = 0.f;
    #pragma unroll
    for (int jj = 0; jj < 7; jj++) {
        const float lp = l[jj] - mx - lse;
        ent -= expf(lp) * lp;
        if (jj == a) lp_a = lp;
    }

    float v = CB1[0];
    for (int k = 0; k < 100; k++) v += m2Tc[(size_t)k * TB + r] * CW[k];

    out[r]          = (float)a;
    out[TB + r]     = lp_a;
    out[2 * TB + r] = ent;
    out[3 * TB + r] = v;
}

// ---------------------------------------------------------------------------
extern "C" void kernel_launch(void* const* d_in, const int* in_sizes, int n_in,
                              void* d_out, int out_size, void* d_ws, size_t ws_size,
                              hipStream_t stream)
{
    const float* x     = (const float*)d_in[0];
    const float* gru0  = (const float*)d_in[1];
    const float* done  = (const float*)d_in[2];
    const int*   act   = (const int*)d_in[3];
    #define AIN(i) ((const float*)d_in[4 + (i)])
    #define CIN(i) ((const float*)d_in[20 + (i)])
    // per-net order: c1w,c1b,c2w,c2b,fw,fb,wih,whh,bih,bhh,h1w,h1b,h2w,h2b,h3w,h3b

    // Workspace:
    // region1 (10,616,832 f): y2 during conv/FC phase; then gi+m1+m2T+hg+cnt.
    // region2 ( 2,097,152 f): feats during FC/gi phase; then hid.
    float* ws = (float*)d_ws;
    float* region1 = ws;
    float* region2 = ws + (size_t)TB * 2592;

    float* y2  = region1;                          // [4096][2592]
    float* gi  = region1;                          // [2][4096][768] (after y2 dead)
    float* m1  = gi  + (size_t)2 * TB * 768;       // [2][4096][200]
    float* m2T = m1  + (size_t)2 * TB * 200;       // [2][100][4096]
    float* hg  = m2T + (size_t)2 * TB * 100;       // [2 pp][64][256]
    int*   cnt = (int*)(hg + 2 * 64 * 256);        // [64]

    float* feats = region2;                        // [2][4096][256]
    float* hid   = region2;                        // [2][4096][256] (after feats dead)

    float* feats_c = feats + (size_t)TB * 256;
    float* gi_c    = gi    + (size_t)TB * 768;
    float* m1_c    = m1    + (size_t)TB * 200;
    float* m2T_c   = m2T   + (size_t)TB * 100;
    float* hid_c   = hid   + (size_t)TB * 256;

    // ---- actor CNN + FC ----
    conv_front2<<<TB, 256, 0, stream>>>(x, AIN(0), AIN(1), AIN(2), AIN(3), y2);
    gemm64<<<dim3(64, 4), 256, 0, stream>>>(y2, AIN(4), AIN(5), feats,
                                            TB, 256, 2592, 1, 0, 0);
    // ---- critic CNN + FC (reuse y2) ----
    conv_front2<<<TB, 256, 0, stream>>>(x, CIN(0), CIN(1), CIN(2), CIN(3), y2);
    gemm64<<<dim3(64, 4), 256, 0, stream>>>(y2, CIN(4), CIN(5), feats_c,
                                            TB, 256, 2592, 1, 0, 0);

    // ---- y2 dead: gi row-major (bih added) ----
    gemm64<<<dim3(64, 12), 256, 0, stream>>>(feats, AIN(6), AIN(8), gi,
                                             TB, 768, 256, 0, 0, 0);
    gemm64<<<dim3(64, 12), 256, 0, stream>>>(feats_c, CIN(6), CIN(8), gi_c,
                                             TB, 768, 256, 0, 0, 0);

    // ---- init h pingpong + counters, then cooperative scan (256 blocks) ----
    scan_init<<<64, 256, 0, stream>>>(gru0, hg, cnt);
    float* out = (float*)d_out;
    {
        const float* gi_p = gi;
        const float* whh_a = AIN(7); const float* whh_c = CIN(7);
        const float* bhh_a = AIN(9); const float* bhh_c = CIN(9);
        const float* done_p = done;
        float* hg_p = hg; int* cnt_p = cnt;
        float* hid_p = hid; float* hT_p = out + 4 * TB;
        void* args[] = {(void*)&gi_p, (void*)&whh_a, (void*)&whh_c,
                        (void*)&bhh_a, (void*)&bhh_c, (void*)&done_p,
                        (void*)&hg_p, (void*)&cnt_p, (void*)&hid_p, (void*)&hT_p};
        hipLaunchCooperativeKernel((void*)gru_scan3, dim3(256), dim3(768),
                                   args, 0, stream);
    }

    // ---- MLPs: m1 reads hid row-major; m2 written transposed for heads ----
    gemm64<<<dim3(64, 4), 256, 0, stream>>>(hid, AIN(10), AIN(11), m1,
                                            TB, 200, 256, 1, 0, 0);
    gemm64<<<dim3(64, 4), 256, 0, stream>>>(hid_c, CIN(10), CIN(11), m1_c,
                                            TB, 200, 256, 1, 0, 0);
    gemm64<<<dim3(64, 2), 256, 0, stream>>>(m1, AIN(12), AIN(13), m2T,
                                            TB, 100, 200, 1, 0, 1);
    gemm64<<<dim3(64, 2), 256, 0, stream>>>(m1_c, CIN(12), CIN(13), m2T_c,
                                            TB, 100, 200, 1, 0, 1);

    // ---- heads ----
    heads<<<TB / 256, 256, 0, stream>>>(m2T, m2T_c, AIN(14), AIN(15),
                                        CIN(14), CIN(15), act, out);
}